// Round 8
// baseline (463.087 us; speedup 1.0000x reference)
//
#include <hip/hip_runtime.h>

#define ROWSB 32     // rows per block; 4 waves x 8 rows (wave == agent group)
#define HIDN 256
#define TT 8
#define EPSI 1e-6f
#define HAS 260      // ha row stride (floats)
#define SVS 260      // sorted-vocab row stride (257 used + 3 INF pad)
#define TBSTR 40
#define NCELL 128
#define WS_LUT_F   (32*SVS)                 // ushort lut[32][128] == 2048 floats
#define WS_DINFO_F (32*SVS + 2048)          // float2 dinfo[32] (base, scale)
#define WS_WMV_F   (32*SVS + 2048 + 64)     // interleaved [j][d][(mu,var)] = 16384 floats

__device__ __forceinline__ void ld4(float* d, const float* p) {
  float4 v = *(const float4*)p;
  d[0] = v.x; d[1] = v.y; d[2] = v.z; d[3] = v.w;
}
__device__ __forceinline__ void ld2(float* d, const float* p) {
  float2 v = *(const float2*)p;
  d[0] = v.x; d[1] = v.y;
}
// Order own-wave LDS write->read without draining the global-load (vmcnt) queue.
__device__ __forceinline__ void lds_fence() {
  asm volatile("s_waitcnt lgkmcnt(0)" ::: "memory");
}
// 8 FMAs for one j: wv = (mu[d0],var[d0],mu[d1],var[d1]); h0/h1 = ha[row0/1][j]
__device__ __forceinline__ void fma8(float4 wv, float h0, float h1,
                                     float* mu0, float* lv0, float* mu1, float* lv1) {
  mu0[0] += h0*wv.x; lv0[0] += h0*wv.y; mu0[1] += h0*wv.z; lv0[1] += h0*wv.w;
  mu1[0] += h1*wv.x; lv1[0] += h1*wv.y; mu1[1] += h1*wv.z; lv1[1] += h1*wv.w;
}

// ---------- pre-pass: per-dim bitonic sort + LUT + (mu,var) weight interleave ----------
__global__ __launch_bounds__(256)
void sort_vocab(const float* __restrict__ vocab,
                const float* __restrict__ Wmu, const float* __restrict__ Wvar,
                float* __restrict__ ws) {
  __shared__ float arr[512];
  const int d = blockIdx.x;
  const int t = threadIdx.x;
  // interleave: ws[WMV + (j*32+d)*2 + {0,1}] = Wmu/Wvar[j][d], j = t
  ws[WS_WMV_F + ((size_t)t*32 + d)*2 + 0] = Wmu[(size_t)t*32 + d];
  ws[WS_WMV_F + ((size_t)t*32 + d)*2 + 1] = Wvar[(size_t)t*32 + d];
  arr[t] = (t < 257) ? vocab[t*32 + d] : 3.0e38f;
  arr[t+256] = (t == 0) ? vocab[256*32 + d] : 3.0e38f;
  __syncthreads();
  for (int k = 2; k <= 512; k <<= 1) {
    for (int j = k >> 1; j > 0; j >>= 1) {
      #pragma unroll
      for (int h = 0; h < 2; ++h) {
        int i = t + h*256;
        int ixj = i ^ j;
        if (ixj > i) {
          float a = arr[i], b = arr[ixj];
          bool up = ((i & k) == 0);
          if ((a > b) == up) { arr[i] = b; arr[ixj] = a; }
        }
      }
      __syncthreads();
    }
  }
  #pragma unroll
  for (int h = 0; h < 2; ++h) {
    int i = t + h*256;
    if (i < SVS) ws[d*SVS + i] = (i < 257) ? arr[i] : 3.0e38f;
  }
  float base = arr[0];
  float maxv = arr[256];
  float scale = (float)NCELL / fmaxf(maxv - base, 1e-30f);
  if (t == 0) {
    float2* dinfo = (float2*)(ws + WS_DINFO_F);
    dinfo[d] = make_float2(base, scale);
  }
  if (t < NCELL) {
    float target = base + (float)t * (maxv - base) * (1.0f/(float)NCELL);
    int lo = 0, hi = 257;
    while (lo < hi) { int mid = (lo+hi)>>1; if (arr[mid] < target) lo = mid+1; else hi = mid; }
    ((unsigned short*)(ws + WS_LUT_F))[d*NCELL + t] = (unsigned short)lo;
  }
}

// ---------- main fused kernel: 8 rows/wave; GEMV = 2 rows x 2 dims / thread ----------
// __launch_bounds__(256,1): grid (512 blocks) caps residency at 2 blocks/CU
// = 8 waves/CU anyway, which the HW sustains even at 256 VGPR/thread — so the
// 256-VGPR cap is free and eliminates the r7 spill (138 MB FETCH / 99 MB WRITE
// of scratch traffic at the (256,2) 128-VGPR cap).
__global__ __launch_bounds__(256, 1)
void mac_fused(const float* __restrict__ hs, const float* __restrict__ eps,
               const float* __restrict__ WQ, const float* __restrict__ bQ,
               const float* __restrict__ WK, const float* __restrict__ bK,
               const float* __restrict__ Wmu, const float* __restrict__ bmu,
               const float* __restrict__ Wvar, const float* __restrict__ bvar,
               const float* __restrict__ vocab,
               const float* __restrict__ Wsum, const float* __restrict__ bsum,
               const float* __restrict__ Whead, const float* __restrict__ bhead,
               const float* __restrict__ ws, float* __restrict__ out, int Btot)
{
  // 80,384 B LDS -> 2 blocks/CU
  __shared__ __align__(16) float ha[ROWSB*HAS];       // wave-private rows; end: comm/o1 alias
  __shared__ __align__(16) float sV[32*SVS];          // sorted vocab [dim][257+INF pad]
  __shared__ __align__(16) unsigned short lut[32*NCELL];
  __shared__ __align__(16) float tokbuf[ROWSB*TBSTR]; // wave-private rows
  __shared__ float ivbuf[ROWSB], finbuf[ROWSB];       // wave-private rows

  const int t   = threadIdx.x;
  const int c4  = t & 63;
  const int w   = t >> 6;         // wave id; rows w*8..w*8+7 (one agent group)
  const int rp  = t >> 4;         // sampling row-pair: rows 2rp, 2rp+1 (in own octet)
  const int dp  = t & 15;         // sampling dim-pair: dims 2dp, 2dp+1
  const int d0u = (c4 << 2) & 31;
  const int tg  = c4 >> 3;        // token slot of this thread's cols
  const int rowbase = blockIdx.x * ROWSB;

  float Qr[8][4], Vr[8][4], Kr[8][4], MSGr[8][4];
  float eosv[4];
  unsigned fin = 0u;

  // ---------------- staging ----------------
  {
    const float* hp = hs + (size_t)(rowbase + w*8)*HIDN + c4*4;
    #pragma unroll
    for (int rr = 0; rr < 8; ++rr)
      *(float4*)&ha[(w*8+rr)*HAS + c4*4] = *(const float4*)(hp + (size_t)rr*HIDN);
  }
  for (int i = t; i < 32*SVS/4; i += 256)              // 2080 float4
    *(float4*)&sV[i*4] = *(const float4*)(ws + (size_t)i*4);
  for (int i = t; i < 512; i += 256)                   // lut: 2048 floats
    ((float4*)lut)[i] = ((const float4*)(ws + WS_LUT_F))[i];
  if (c4 < 8) finbuf[w*8 + c4] = 0.f;
  ld4(eosv, vocab + 256*32 + d0u);
  {
    float bq[4], bk[4];
    ld4(bq, bQ + c4*4); ld4(bk, bK + c4*4);
    #pragma unroll
    for (int rr = 0; rr < 8; ++rr) {
      #pragma unroll
      for (int k = 0; k < 4; ++k) { Qr[rr][k] = bq[k]; Vr[rr][k] = bk[k]; }
    }
  }
  float dbr[2], dsr[2];
  {
    float t0[4];
    ld4(t0, ws + WS_DINFO_F + dp*4);   // dinfo[2dp], dinfo[2dp+1]
    dbr[0]=t0[0]; dsr[0]=t0[1]; dbr[1]=t0[2]; dsr[1]=t0[3];
  }
  float bm[2], bv[2];
  ld2(bm, bmu + dp*2); ld2(bv, bvar + dp*2);
  lds_fence();   // own-wave ha writes ordered before cross-lane reads

  // ------------- initial GEMM: Q = hs@WQ + bQ ; V = hs@WK + bK -------------
  #pragma unroll 2
  for (int jq = 0; jq < 64; ++jq) {
    float hsq[8][4];
    #pragma unroll
    for (int rr = 0; rr < 8; ++rr) ld4(hsq[rr], &ha[(w*8+rr)*HAS + jq*4]);
    #pragma unroll
    for (int m = 0; m < 4; ++m) {
      float wq[4], wk[4];
      ld4(wq, WQ + (size_t)(jq*4+m)*HIDN + c4*4);
      ld4(wk, WK + (size_t)(jq*4+m)*HIDN + c4*4);
      #pragma unroll
      for (int rr = 0; rr < 8; ++rr) {
        #pragma unroll
        for (int k = 0; k < 4; ++k) {
          Qr[rr][k] += hsq[rr][m]*wq[k];
          Vr[rr][k] += hsq[rr][m]*wk[k];
        }
      }
    }
  }
  {
    float bk[4]; ld4(bk, bK + c4*4);
    #pragma unroll
    for (int rr = 0; rr < 8; ++rr) {
      #pragma unroll
      for (int k = 0; k < 4; ++k) {
        Qr[rr][k] *= (1.0f/256.0f);   // bake NF^2: logit = -(Qr*Kr)
        Kr[rr][k]   = bk[k];
        MSGr[rr][k] = 0.f;
      }
    }
  }

  __syncthreads();   // sV/lut visible block-wide; the only pre-final barrier

  // ---------------- token recurrence (wave-private, lgkm-only fences) ----------------
  for (int it = 0; it < TT; ++it) {
    if (it > 0) {
      const float* Wr = WK + (size_t)((it-1)*32)*HIDN + c4*4;
      #pragma unroll 2
      for (int cq = 0; cq < 8; ++cq) {
        float tq[8][4];
        #pragma unroll
        for (int rr = 0; rr < 8; ++rr) ld4(tq[rr], &tokbuf[(w*8+rr)*TBSTR + cq*4]);
        #pragma unroll
        for (int m = 0; m < 4; ++m) {
          float wv[4]; ld4(wv, Wr + (size_t)(cq*4+m)*HIDN);
          #pragma unroll
          for (int rr = 0; rr < 8; ++rr) {
            #pragma unroll
            for (int k = 0; k < 4; ++k) Kr[rr][k] += tq[rr][m]*wv[k];
          }
        }
      }
    }

    // eps prefetch for both sampling rows
    float ep0[2], ep1[2];
    ld2(ep0, eps + ((size_t)it*Btot + rowbase + 2*rp)*32 + dp*2);
    ld2(ep1, eps + ((size_t)it*Btot + rowbase + 2*rp+1)*32 + dp*2);

    // --- softmax(-(Q*K)) without max-sub (|logit|<~2e-3); store e*V; 1/s in ivbuf ---
    #pragma unroll
    for (int rr = 0; rr < 8; ++rr) {
      float e[4]; float s = 0.f;
      #pragma unroll
      for (int k = 0; k < 4; ++k) { e[k] = __expf(-(Qr[rr][k]*Kr[rr][k])); s += e[k]; }
      #pragma unroll
      for (int off = 32; off >= 1; off >>= 1) s += __shfl_xor(s, off);
      if (c4 == rr) ivbuf[w*8+rr] = 1.0f / s;
      *(float4*)&ha[(w*8+rr)*HAS + c4*4] =
          make_float4(e[0]*Vr[rr][0], e[1]*Vr[rr][1], e[2]*Vr[rr][2], e[3]*Vr[rr][3]);
    }
    lds_fence();

    // --- GEMV (2 rows x 2 dims/thread, reg-double-buffered weight stream) ---
    float mu0[2]={0,0}, lv0[2]={0,0}, mu1[2]={0,0}, lv1[2]={0,0};
    {
      const float* wmv  = ws + WS_WMV_F + dp*4;   // + j*64 per weight row j
      const float* har0 = &ha[(2*rp)*HAS];
      const float* har1 = &ha[(2*rp+1)*HAS];
      float4 wb0[8], wb1[8];
      #pragma unroll
      for (int u = 0; u < 8; ++u) wb0[u] = *(const float4*)(wmv + (size_t)u*64);
      #pragma unroll 1
      for (int bb = 0; bb < 16; ++bb) {
        {   // batch b = 2bb (weights in wb0); prefetch b+1 into wb1
          const int b = 2*bb;
          float4 h0a = *(const float4*)(har0 + b*8);
          float4 h1a = *(const float4*)(har1 + b*8);
          float4 h0b = *(const float4*)(har0 + b*8 + 4);
          float4 h1b = *(const float4*)(har1 + b*8 + 4);
          const float* wp = wmv + (size_t)(b+1)*512;
          #pragma unroll
          for (int u = 0; u < 8; ++u) wb1[u] = *(const float4*)(wp + (size_t)u*64);
          fma8(wb0[0], h0a.x, h1a.x, mu0, lv0, mu1, lv1);
          fma8(wb0[1], h0a.y, h1a.y, mu0, lv0, mu1, lv1);
          fma8(wb0[2], h0a.z, h1a.z, mu0, lv0, mu1, lv1);
          fma8(wb0[3], h0a.w, h1a.w, mu0, lv0, mu1, lv1);
          fma8(wb0[4], h0b.x, h1b.x, mu0, lv0, mu1, lv1);
          fma8(wb0[5], h0b.y, h1b.y, mu0, lv0, mu1, lv1);
          fma8(wb0[6], h0b.z, h1b.z, mu0, lv0, mu1, lv1);
          fma8(wb0[7], h0b.w, h1b.w, mu0, lv0, mu1, lv1);
        }
        {   // batch b = 2bb+1 (weights in wb1); prefetch b+1 into wb0
          const int b = 2*bb+1;
          float4 h0a = *(const float4*)(har0 + b*8);
          float4 h1a = *(const float4*)(har1 + b*8);
          float4 h0b = *(const float4*)(har0 + b*8 + 4);
          float4 h1b = *(const float4*)(har1 + b*8 + 4);
          if (bb < 15) {
            const float* wp = wmv + (size_t)(b+1)*512;
            #pragma unroll
            for (int u = 0; u < 8; ++u) wb0[u] = *(const float4*)(wp + (size_t)u*64);
          }
          fma8(wb1[0], h0a.x, h1a.x, mu0, lv0, mu1, lv1);
          fma8(wb1[1], h0a.y, h1a.y, mu0, lv0, mu1, lv1);
          fma8(wb1[2], h0a.z, h1a.z, mu0, lv0, mu1, lv1);
          fma8(wb1[3], h0a.w, h1a.w, mu0, lv0, mu1, lv1);
          fma8(wb1[4], h0b.x, h1b.x, mu0, lv0, mu1, lv1);
          fma8(wb1[5], h0b.y, h1b.y, mu0, lv0, mu1, lv1);
          fma8(wb1[6], h0b.z, h1b.z, mu0, lv0, mu1, lv1);
          fma8(wb1[7], h0b.w, h1b.w, mu0, lv0, mu1, lv1);
        }
      }
    }
    // --- sample + quantize via sorted scan (all LDS) ---
    {
      float ivr0 = ivbuf[2*rp],  ivr1 = ivbuf[2*rp+1];
      float msk0 = 1.0f - finbuf[2*rp], msk1 = 1.0f - finbuf[2*rp+1];
      float md0[2], md1[2];
      #pragma unroll
      for (int d = 0; d < 2; ++d) {
        const int dim = 2*dp + d;
        const float* sp = &sV[dim*SVS];
        {
          float mu = mu0[d]*ivr0 + bm[d];
          float lv = lv0[d]*ivr0 + bv[d];
          float x  = ep0[d]*__expf(0.5f*lv) + mu;
          int c = (int)((x - dbr[d]) * dsr[d]);
          c = min(max(c, 0), NCELL-1);
          int idx = (int)lut[dim*NCELL + c];
          float v = sp[idx];
          while (v < x) { ++idx; v = sp[idx]; }
          float dn = v - x;
          float dpv = (idx > 0) ? (x - sp[idx-1]) : 3.0e38f;
          md0[d] = fminf(dn, dpv);
        }
        {
          float mu = mu1[d]*ivr1 + bm[d];
          float lv = lv1[d]*ivr1 + bv[d];
          float x  = ep1[d]*__expf(0.5f*lv) + mu;
          int c = (int)((x - dbr[d]) * dsr[d]);
          c = min(max(c, 0), NCELL-1);
          int idx = (int)lut[dim*NCELL + c];
          float v = sp[idx];
          while (v < x) { ++idx; v = sp[idx]; }
          float dn = v - x;
          float dpv = (idx > 0) ? (x - sp[idx-1]) : 3.0e38f;
          md1[d] = fminf(dn, dpv);
        }
      }
      *(float2*)&tokbuf[(2*rp)*TBSTR + dp*2]   = make_float2(md0[0]*md0[0]*msk0, md0[1]*md0[1]*msk0);
      *(float2*)&tokbuf[(2*rp+1)*TBSTR + dp*2] = make_float2(md1[0]*md1[0]*msk1, md1[1]*md1[1]*msk1);
    }
    lds_fence();

    // --- hit detection + message update ---
    {
      float tokr[8][4];
      #pragma unroll
      for (int rr = 0; rr < 8; ++rr) ld4(tokr[rr], &tokbuf[(w*8+rr)*TBSTR + d0u]);
      unsigned newfin = fin;
      #pragma unroll
      for (int rr = 0; rr < 8; ++rr) {
        float pd = 0.f, ed = 0.f;
        #pragma unroll
        for (int k = 0; k < 4; ++k) { float dm = tokr[rr][k]-MSGr[rr][k]; pd += dm*dm; }
        if (tg == 0) {
          #pragma unroll
          for (int k = 0; k < 4; ++k) { float de = tokr[rr][k]-eosv[k]; ed += de*de; }
        }
        pd += __shfl_xor(pd, 1); ed += __shfl_xor(ed, 1);
        pd += __shfl_xor(pd, 2); ed += __shfl_xor(ed, 2);
        pd += __shfl_xor(pd, 4); ed += __shfl_xor(ed, 4);
        bool lane_hit = (tg < it && pd < EPSI) || (tg == 0 && ed < EPSI);
        bool hit = (__ballot(lane_hit) != 0ull);
        if (hit) {
          if ((tg == it) && !((fin >> rr) & 1u)) {
            #pragma unroll
            for (int k = 0; k < 4; ++k) tokr[rr][k] = eosv[k];
          }
          newfin |= (1u << rr);
        }
        if (tg == it) {
          #pragma unroll
          for (int k = 0; k < 4; ++k) MSGr[rr][k] = tokr[rr][k];
        }
      }
      if (tg == it) {
        #pragma unroll
        for (int rr = 0; rr < 8; ++rr)
          *(float4*)&tokbuf[(w*8+rr)*TBSTR + d0u] =
              make_float4(MSGr[rr][0], MSGr[rr][1], MSGr[rr][2], MSGr[rr][3]);
      }
      if (c4 < 8) finbuf[w*8+c4] = ((newfin >> c4) & 1u) ? 1.f : 0.f;
      fin = newfin;
    }
    lds_fence();
  }

  // ---------------- final: comm sum + two block-coop GEMVs + relu ----------------
  __syncthreads();                 // all waves done with ha before aliasing
  float* commb = ha;               // [4][HAS] rows 0..3
  float* o1    = ha + 4*HAS;       // [4][HAS] rows 4..7
  {
    float cs[4] = {0,0,0,0};
    #pragma unroll
    for (int rr = 0; rr < 8; ++rr) {
      #pragma unroll
      for (int k = 0; k < 4; ++k) cs[k] += MSGr[rr][k];
    }
    const float i7 = 1.0f/7.0f;
    *(float4*)&commb[w*HAS + c4*4] = make_float4(cs[0]*i7, cs[1]*i7, cs[2]*i7, cs[3]*i7);
  }
  __syncthreads();
  {
    float bs = bsum[t];
    float a1[4] = {bs, bs, bs, bs};
    #pragma unroll 2
    for (int jq = 0; jq < 64; ++jq) {
      float w4[4];
      #pragma unroll
      for (int m = 0; m < 4; ++m) w4[m] = Wsum[(size_t)(jq*4+m)*HIDN + t];
      #pragma unroll
      for (int g = 0; g < 4; ++g) {
        float c[4]; ld4(c, &commb[g*HAS + jq*4]);   // uniform broadcast
        a1[g] += c[0]*w4[0] + c[1]*w4[1] + c[2]*w4[2] + c[3]*w4[3];
      }
    }
    #pragma unroll
    for (int g = 0; g < 4; ++g) o1[g*HAS + t] = a1[g];
  }
  __syncthreads();
  {
    float bh = bhead[t];
    float a2[4] = {bh, bh, bh, bh};
    #pragma unroll 2
    for (int jq = 0; jq < 64; ++jq) {
      float w4[4];
      #pragma unroll
      for (int m = 0; m < 4; ++m) w4[m] = Whead[(size_t)(jq*4+m)*HIDN + t];
      #pragma unroll
      for (int g = 0; g < 4; ++g) {
        float c[4]; ld4(c, &o1[g*HAS + jq*4]);
        a2[g] += c[0]*w4[0] + c[1]*w4[1] + c[2]*w4[2] + c[3]*w4[3];
      }
    }
    #pragma unroll
    for (int g = 0; g < 4; ++g) {
      float r = fmaxf(a2[g], 0.f);
      #pragma unroll
      for (int rr = 0; rr < 8; ++rr)
        out[(size_t)(rowbase + g*8 + rr)*HIDN + t] = r;
    }
  }
}

extern "C" void kernel_launch(void* const* d_in, const int* in_sizes, int n_in,
                              void* d_out, int out_size, void* d_ws, size_t ws_size,
                              hipStream_t stream) {
    const float* hs    = (const float*)d_in[0];
    const float* eps   = (const float*)d_in[1];
    const float* WQ    = (const float*)d_in[2];
    const float* bQ    = (const float*)d_in[3];
    const float* WK    = (const float*)d_in[4];
    const float* bK    = (const float*)d_in[5];
    const float* Wmu   = (const float*)d_in[6];
    const float* bmu   = (const float*)d_in[7];
    const float* Wvar  = (const float*)d_in[8];
    const float* bvar  = (const float*)d_in[9];
    const float* vocab = (const float*)d_in[10];
    const float* Wsum  = (const float*)d_in[11];
    const float* bsum  = (const float*)d_in[12];
    const float* Whead = (const float*)d_in[13];
    const float* bhead = (const float*)d_in[14];
    float* o = (float*)d_out;
    float* wsf = (float*)d_ws;
    int Btot = in_sizes[0] / HIDN;
    hipLaunchKernelGGL(sort_vocab, dim3(32), dim3(256), 0, stream, vocab, Wmu, Wvar, wsf);
    hipLaunchKernelGGL(mac_fused, dim3(Btot / ROWSB), dim3(256), 0, stream,
                       hs, eps, WQ, bQ, WK, bK, Wmu, bmu, Wvar, bvar,
                       vocab, Wsum, bsum, Whead, bhead, wsf, o, Btot);
}

// Round 9
// 415.790 us; speedup vs baseline: 1.1138x; 1.1138x over previous
//
#include <hip/hip_runtime.h>

#define ROWSB 64     // rows per block; 8 waves x 8 rows (wave == agent group); 1 block/CU
#define BLK  512
#define HIDN 256
#define TT 8
#define EPSI 1e-6f
#define HAS 260      // ha row stride (floats)
#define SVS 260      // sorted-vocab row stride (257 used + 3 INF pad)
#define TBSTR 40
#define NCELL 128
#define WS_LUT_F   (32*SVS)                 // ushort lut[32][128] == 2048 floats
#define WS_DINFO_F (32*SVS + 2048)          // float2 dinfo[32] (base, scale)
#define WS_WMV_F   (32*SVS + 2048 + 64)     // interleaved [j][d][(mu,var)] = 16384 floats

__device__ __forceinline__ void ld4(float* d, const float* p) {
  float4 v = *(const float4*)p;
  d[0] = v.x; d[1] = v.y; d[2] = v.z; d[3] = v.w;
}
__device__ __forceinline__ void ld2(float* d, const float* p) {
  float2 v = *(const float2*)p;
  d[0] = v.x; d[1] = v.y;
}
// Order own-wave LDS write->read without draining the global-load (vmcnt) queue.
__device__ __forceinline__ void lds_fence() {
  asm volatile("s_waitcnt lgkmcnt(0)" ::: "memory");
}
// 8 FMAs for one j: wv = (mu[d0],var[d0],mu[d1],var[d1]); h0/h1 = ha[row0/1][j]
__device__ __forceinline__ void fma8(float4 wv, float h0, float h1,
                                     float* mu0, float* lv0, float* mu1, float* lv1) {
  mu0[0] += h0*wv.x; lv0[0] += h0*wv.y; mu0[1] += h0*wv.z; lv0[1] += h0*wv.w;
  mu1[0] += h1*wv.x; lv1[0] += h1*wv.y; mu1[1] += h1*wv.z; lv1[1] += h1*wv.w;
}

// ---------- pre-pass: per-dim bitonic sort + LUT + (mu,var) weight interleave ----------
__global__ __launch_bounds__(256)
void sort_vocab(const float* __restrict__ vocab,
                const float* __restrict__ Wmu, const float* __restrict__ Wvar,
                float* __restrict__ ws) {
  __shared__ float arr[512];
  const int d = blockIdx.x;
  const int t = threadIdx.x;
  ws[WS_WMV_F + ((size_t)t*32 + d)*2 + 0] = Wmu[(size_t)t*32 + d];
  ws[WS_WMV_F + ((size_t)t*32 + d)*2 + 1] = Wvar[(size_t)t*32 + d];
  arr[t] = (t < 257) ? vocab[t*32 + d] : 3.0e38f;
  arr[t+256] = (t == 0) ? vocab[256*32 + d] : 3.0e38f;
  __syncthreads();
  for (int k = 2; k <= 512; k <<= 1) {
    for (int j = k >> 1; j > 0; j >>= 1) {
      #pragma unroll
      for (int h = 0; h < 2; ++h) {
        int i = t + h*256;
        int ixj = i ^ j;
        if (ixj > i) {
          float a = arr[i], b = arr[ixj];
          bool up = ((i & k) == 0);
          if ((a > b) == up) { arr[i] = b; arr[ixj] = a; }
        }
      }
      __syncthreads();
    }
  }
  #pragma unroll
  for (int h = 0; h < 2; ++h) {
    int i = t + h*256;
    if (i < SVS) ws[d*SVS + i] = (i < 257) ? arr[i] : 3.0e38f;
  }
  float base = arr[0];
  float maxv = arr[256];
  float scale = (float)NCELL / fmaxf(maxv - base, 1e-30f);
  if (t == 0) {
    float2* dinfo = (float2*)(ws + WS_DINFO_F);
    dinfo[d] = make_float2(base, scale);
  }
  if (t < NCELL) {
    float target = base + (float)t * (maxv - base) * (1.0f/(float)NCELL);
    int lo = 0, hi = 257;
    while (lo < hi) { int mid = (lo+hi)>>1; if (arr[mid] < target) lo = mid+1; else hi = mid; }
    ((unsigned short*)(ws + WS_LUT_F))[d*NCELL + t] = (unsigned short)lo;
  }
}

// ---------- main fused kernel: 512 threads = 8 waves x 8 rows; 1 block/CU ----------
// r7/r8 lesson: the pipelined GEMV needs ~168 VGPR (no spill only above the
// 128 cap) AND 8 waves/CU. 256-thread blocks can't have both (2 blocks needs
// VGPR<=128 -> spill). A 512-thread block guarantees 8 resident waves at
// dispatch with the 256-VGPR cap of __launch_bounds__(512,1).
__global__ __launch_bounds__(BLK, 1)
void mac_fused(const float* __restrict__ hs, const float* __restrict__ eps,
               const float* __restrict__ WQ, const float* __restrict__ bQ,
               const float* __restrict__ WK, const float* __restrict__ bK,
               const float* __restrict__ Wmu, const float* __restrict__ bmu,
               const float* __restrict__ Wvar, const float* __restrict__ bvar,
               const float* __restrict__ vocab,
               const float* __restrict__ Wsum, const float* __restrict__ bsum,
               const float* __restrict__ Whead, const float* __restrict__ bhead,
               const float* __restrict__ ws, float* __restrict__ out, int Btot)
{
  // 118.8 KB LDS -> 1 block/CU (which is the whole plan)
  __shared__ __align__(16) float ha[ROWSB*HAS];       // wave-private rows; end: comm/o1 alias
  __shared__ __align__(16) float sV[32*SVS];          // sorted vocab [dim][257+INF pad]
  __shared__ __align__(16) unsigned short lut[32*NCELL];
  __shared__ __align__(16) float tokbuf[ROWSB*TBSTR]; // wave-private rows
  __shared__ float ivbuf[ROWSB], finbuf[ROWSB];       // wave-private rows

  const int t   = threadIdx.x;
  const int c4  = t & 63;
  const int w   = t >> 6;         // wave id 0..7; rows w*8..w*8+7 (one agent group)
  const int rp  = t >> 4;         // sampling row-pair 0..31: rows 2rp, 2rp+1 (own octet)
  const int dp  = t & 15;         // sampling dim-pair: dims 2dp, 2dp+1
  const int d0u = (c4 << 2) & 31;
  const int tg  = c4 >> 3;        // token slot of this thread's cols
  const int rowbase = blockIdx.x * ROWSB;

  float Qr[8][4], Vr[8][4], Kr[8][4], MSGr[8][4];
  float eosv[4];
  unsigned fin = 0u;

  // ---------------- staging ----------------
  {
    const float* hp = hs + (size_t)(rowbase + w*8)*HIDN + c4*4;
    #pragma unroll
    for (int rr = 0; rr < 8; ++rr)
      *(float4*)&ha[(w*8+rr)*HAS + c4*4] = *(const float4*)(hp + (size_t)rr*HIDN);
  }
  for (int i = t; i < 32*SVS/4; i += BLK)              // 2080 float4
    *(float4*)&sV[i*4] = *(const float4*)(ws + (size_t)i*4);
  for (int i = t; i < 512; i += BLK)                   // lut: 2048 floats
    ((float4*)lut)[i] = ((const float4*)(ws + WS_LUT_F))[i];
  if (c4 < 8) finbuf[w*8 + c4] = 0.f;
  ld4(eosv, vocab + 256*32 + d0u);
  {
    float bq[4], bk[4];
    ld4(bq, bQ + c4*4); ld4(bk, bK + c4*4);
    #pragma unroll
    for (int rr = 0; rr < 8; ++rr) {
      #pragma unroll
      for (int k = 0; k < 4; ++k) { Qr[rr][k] = bq[k]; Vr[rr][k] = bk[k]; }
    }
  }
  float dbr[2], dsr[2];
  {
    float t0[4];
    ld4(t0, ws + WS_DINFO_F + dp*4);   // dinfo[2dp], dinfo[2dp+1]
    dbr[0]=t0[0]; dsr[0]=t0[1]; dbr[1]=t0[2]; dsr[1]=t0[3];
  }
  float bm[2], bv[2];
  ld2(bm, bmu + dp*2); ld2(bv, bvar + dp*2);
  lds_fence();   // own-wave ha writes ordered before cross-lane reads

  // ------------- initial GEMM: Q = hs@WQ + bQ ; V = hs@WK + bK -------------
  #pragma unroll 2
  for (int jq = 0; jq < 64; ++jq) {
    float hsq[8][4];
    #pragma unroll
    for (int rr = 0; rr < 8; ++rr) ld4(hsq[rr], &ha[(w*8+rr)*HAS + jq*4]);
    #pragma unroll
    for (int m = 0; m < 4; ++m) {
      float wq[4], wk[4];
      ld4(wq, WQ + (size_t)(jq*4+m)*HIDN + c4*4);
      ld4(wk, WK + (size_t)(jq*4+m)*HIDN + c4*4);
      #pragma unroll
      for (int rr = 0; rr < 8; ++rr) {
        #pragma unroll
        for (int k = 0; k < 4; ++k) {
          Qr[rr][k] += hsq[rr][m]*wq[k];
          Vr[rr][k] += hsq[rr][m]*wk[k];
        }
      }
    }
  }
  {
    float bk[4]; ld4(bk, bK + c4*4);
    #pragma unroll
    for (int rr = 0; rr < 8; ++rr) {
      #pragma unroll
      for (int k = 0; k < 4; ++k) {
        Qr[rr][k] *= (1.0f/256.0f);   // bake NF^2: logit = -(Qr*Kr)
        Kr[rr][k]   = bk[k];
        MSGr[rr][k] = 0.f;
      }
    }
  }

  __syncthreads();   // sV/lut visible block-wide; the only pre-final barrier

  // ---------------- token recurrence (wave-private, lgkm-only fences) ----------------
  for (int it = 0; it < TT; ++it) {
    if (it > 0) {
      const float* Wr = WK + (size_t)((it-1)*32)*HIDN + c4*4;
      #pragma unroll 2
      for (int cq = 0; cq < 8; ++cq) {
        float tq[8][4];
        #pragma unroll
        for (int rr = 0; rr < 8; ++rr) ld4(tq[rr], &tokbuf[(w*8+rr)*TBSTR + cq*4]);
        #pragma unroll
        for (int m = 0; m < 4; ++m) {
          float wv[4]; ld4(wv, Wr + (size_t)(cq*4+m)*HIDN);
          #pragma unroll
          for (int rr = 0; rr < 8; ++rr) {
            #pragma unroll
            for (int k = 0; k < 4; ++k) Kr[rr][k] += tq[rr][m]*wv[k];
          }
        }
      }
    }

    // eps prefetch for both sampling rows
    float ep0[2], ep1[2];
    ld2(ep0, eps + ((size_t)it*Btot + rowbase + 2*rp)*32 + dp*2);
    ld2(ep1, eps + ((size_t)it*Btot + rowbase + 2*rp+1)*32 + dp*2);

    // --- softmax(-(Q*K)) without max-sub (|logit|<~2e-3); store e*V; 1/s in ivbuf ---
    #pragma unroll
    for (int rr = 0; rr < 8; ++rr) {
      float e[4]; float s = 0.f;
      #pragma unroll
      for (int k = 0; k < 4; ++k) { e[k] = __expf(-(Qr[rr][k]*Kr[rr][k])); s += e[k]; }
      #pragma unroll
      for (int off = 32; off >= 1; off >>= 1) s += __shfl_xor(s, off);
      if (c4 == rr) ivbuf[w*8+rr] = 1.0f / s;
      *(float4*)&ha[(w*8+rr)*HAS + c4*4] =
          make_float4(e[0]*Vr[rr][0], e[1]*Vr[rr][1], e[2]*Vr[rr][2], e[3]*Vr[rr][3]);
    }
    lds_fence();

    // --- GEMV (2 rows x 2 dims/thread, reg-double-buffered weight stream) ---
    float mu0[2]={0,0}, lv0[2]={0,0}, mu1[2]={0,0}, lv1[2]={0,0};
    {
      const float* wmv  = ws + WS_WMV_F + dp*4;   // + j*64 per weight row j
      const float* har0 = &ha[(2*rp)*HAS];
      const float* har1 = &ha[(2*rp+1)*HAS];
      float4 wb0[8], wb1[8];
      #pragma unroll
      for (int u = 0; u < 8; ++u) wb0[u] = *(const float4*)(wmv + (size_t)u*64);
      #pragma unroll 1
      for (int bb = 0; bb < 16; ++bb) {
        {   // batch b = 2bb (weights in wb0); prefetch b+1 into wb1
          const int b = 2*bb;
          float4 h0a = *(const float4*)(har0 + b*8);
          float4 h1a = *(const float4*)(har1 + b*8);
          float4 h0b = *(const float4*)(har0 + b*8 + 4);
          float4 h1b = *(const float4*)(har1 + b*8 + 4);
          const float* wp = wmv + (size_t)(b+1)*512;
          #pragma unroll
          for (int u = 0; u < 8; ++u) wb1[u] = *(const float4*)(wp + (size_t)u*64);
          fma8(wb0[0], h0a.x, h1a.x, mu0, lv0, mu1, lv1);
          fma8(wb0[1], h0a.y, h1a.y, mu0, lv0, mu1, lv1);
          fma8(wb0[2], h0a.z, h1a.z, mu0, lv0, mu1, lv1);
          fma8(wb0[3], h0a.w, h1a.w, mu0, lv0, mu1, lv1);
          fma8(wb0[4], h0b.x, h1b.x, mu0, lv0, mu1, lv1);
          fma8(wb0[5], h0b.y, h1b.y, mu0, lv0, mu1, lv1);
          fma8(wb0[6], h0b.z, h1b.z, mu0, lv0, mu1, lv1);
          fma8(wb0[7], h0b.w, h1b.w, mu0, lv0, mu1, lv1);
        }
        {   // batch b = 2bb+1 (weights in wb1); prefetch b+1 into wb0
          const int b = 2*bb+1;
          float4 h0a = *(const float4*)(har0 + b*8);
          float4 h1a = *(const float4*)(har1 + b*8);
          float4 h0b = *(const float4*)(har0 + b*8 + 4);
          float4 h1b = *(const float4*)(har1 + b*8 + 4);
          if (bb < 15) {
            const float* wp = wmv + (size_t)(b+1)*512;
            #pragma unroll
            for (int u = 0; u < 8; ++u) wb0[u] = *(const float4*)(wp + (size_t)u*64);
          }
          fma8(wb1[0], h0a.x, h1a.x, mu0, lv0, mu1, lv1);
          fma8(wb1[1], h0a.y, h1a.y, mu0, lv0, mu1, lv1);
          fma8(wb1[2], h0a.z, h1a.z, mu0, lv0, mu1, lv1);
          fma8(wb1[3], h0a.w, h1a.w, mu0, lv0, mu1, lv1);
          fma8(wb1[4], h0b.x, h1b.x, mu0, lv0, mu1, lv1);
          fma8(wb1[5], h0b.y, h1b.y, mu0, lv0, mu1, lv1);
          fma8(wb1[6], h0b.z, h1b.z, mu0, lv0, mu1, lv1);
          fma8(wb1[7], h0b.w, h1b.w, mu0, lv0, mu1, lv1);
        }
      }
    }
    // --- sample + quantize via sorted scan (all LDS) ---
    {
      float ivr0 = ivbuf[2*rp],  ivr1 = ivbuf[2*rp+1];
      float msk0 = 1.0f - finbuf[2*rp], msk1 = 1.0f - finbuf[2*rp+1];
      float md0[2], md1[2];
      #pragma unroll
      for (int d = 0; d < 2; ++d) {
        const int dim = 2*dp + d;
        const float* sp = &sV[dim*SVS];
        {
          float mu = mu0[d]*ivr0 + bm[d];
          float lv = lv0[d]*ivr0 + bv[d];
          float x  = ep0[d]*__expf(0.5f*lv) + mu;
          int c = (int)((x - dbr[d]) * dsr[d]);
          c = min(max(c, 0), NCELL-1);
          int idx = (int)lut[dim*NCELL + c];
          float v = sp[idx];
          while (v < x) { ++idx; v = sp[idx]; }
          float dn = v - x;
          float dpv = (idx > 0) ? (x - sp[idx-1]) : 3.0e38f;
          md0[d] = fminf(dn, dpv);
        }
        {
          float mu = mu1[d]*ivr1 + bm[d];
          float lv = lv1[d]*ivr1 + bv[d];
          float x  = ep1[d]*__expf(0.5f*lv) + mu;
          int c = (int)((x - dbr[d]) * dsr[d]);
          c = min(max(c, 0), NCELL-1);
          int idx = (int)lut[dim*NCELL + c];
          float v = sp[idx];
          while (v < x) { ++idx; v = sp[idx]; }
          float dn = v - x;
          float dpv = (idx > 0) ? (x - sp[idx-1]) : 3.0e38f;
          md1[d] = fminf(dn, dpv);
        }
      }
      *(float2*)&tokbuf[(2*rp)*TBSTR + dp*2]   = make_float2(md0[0]*md0[0]*msk0, md0[1]*md0[1]*msk0);
      *(float2*)&tokbuf[(2*rp+1)*TBSTR + dp*2] = make_float2(md1[0]*md1[0]*msk1, md1[1]*md1[1]*msk1);
    }
    lds_fence();

    // --- hit detection + message update ---
    {
      float tokr[8][4];
      #pragma unroll
      for (int rr = 0; rr < 8; ++rr) ld4(tokr[rr], &tokbuf[(w*8+rr)*TBSTR + d0u]);
      unsigned newfin = fin;
      #pragma unroll
      for (int rr = 0; rr < 8; ++rr) {
        float pd = 0.f, ed = 0.f;
        #pragma unroll
        for (int k = 0; k < 4; ++k) { float dm = tokr[rr][k]-MSGr[rr][k]; pd += dm*dm; }
        if (tg == 0) {
          #pragma unroll
          for (int k = 0; k < 4; ++k) { float de = tokr[rr][k]-eosv[k]; ed += de*de; }
        }
        pd += __shfl_xor(pd, 1); ed += __shfl_xor(ed, 1);
        pd += __shfl_xor(pd, 2); ed += __shfl_xor(ed, 2);
        pd += __shfl_xor(pd, 4); ed += __shfl_xor(ed, 4);
        bool lane_hit = (tg < it && pd < EPSI) || (tg == 0 && ed < EPSI);
        bool hit = (__ballot(lane_hit) != 0ull);
        if (hit) {
          if ((tg == it) && !((fin >> rr) & 1u)) {
            #pragma unroll
            for (int k = 0; k < 4; ++k) tokr[rr][k] = eosv[k];
          }
          newfin |= (1u << rr);
        }
        if (tg == it) {
          #pragma unroll
          for (int k = 0; k < 4; ++k) MSGr[rr][k] = tokr[rr][k];
        }
      }
      if (tg == it) {
        #pragma unroll
        for (int rr = 0; rr < 8; ++rr)
          *(float4*)&tokbuf[(w*8+rr)*TBSTR + d0u] =
              make_float4(MSGr[rr][0], MSGr[rr][1], MSGr[rr][2], MSGr[rr][3]);
      }
      if (c4 < 8) finbuf[w*8+c4] = ((newfin >> c4) & 1u) ? 1.f : 0.f;
      fin = newfin;
    }
    lds_fence();
  }

  // ---------------- final: comm sums + two block-coop GEMVs + relu ----------------
  __syncthreads();                 // all waves done with ha before aliasing
  float* commb = ha;               // [8][HAS] rows 0..7 (one per agent group/wave)
  float* o1    = ha + 8*HAS;       // [8][HAS] rows 8..15
  {
    float cs[4] = {0,0,0,0};
    #pragma unroll
    for (int rr = 0; rr < 8; ++rr) {
      #pragma unroll
      for (int k = 0; k < 4; ++k) cs[k] += MSGr[rr][k];
    }
    const float i7 = 1.0f/7.0f;
    *(float4*)&commb[w*HAS + c4*4] = make_float4(cs[0]*i7, cs[1]*i7, cs[2]*i7, cs[3]*i7);
  }
  __syncthreads();
  const int col = t & 255;         // output column
  const int hf  = t >> 8;          // group half: groups 4hf..4hf+3
  {
    float bs = bsum[col];
    float a1[4] = {bs, bs, bs, bs};
    #pragma unroll 2
    for (int jq = 0; jq < 64; ++jq) {
      float w4[4];
      #pragma unroll
      for (int m = 0; m < 4; ++m) w4[m] = Wsum[(size_t)(jq*4+m)*HIDN + col];
      #pragma unroll
      for (int g = 0; g < 4; ++g) {
        float c[4]; ld4(c, &commb[(4*hf+g)*HAS + jq*4]);   // wave-uniform broadcast
        a1[g] += c[0]*w4[0] + c[1]*w4[1] + c[2]*w4[2] + c[3]*w4[3];
      }
    }
    #pragma unroll
    for (int g = 0; g < 4; ++g) o1[(4*hf+g)*HAS + col] = a1[g];
  }
  __syncthreads();
  {
    float bh = bhead[col];
    float a2[4] = {bh, bh, bh, bh};
    #pragma unroll 2
    for (int jq = 0; jq < 64; ++jq) {
      float w4[4];
      #pragma unroll
      for (int m = 0; m < 4; ++m) w4[m] = Whead[(size_t)(jq*4+m)*HIDN + col];
      #pragma unroll
      for (int g = 0; g < 4; ++g) {
        float c[4]; ld4(c, &o1[(4*hf+g)*HAS + jq*4]);
        a2[g] += c[0]*w4[0] + c[1]*w4[1] + c[2]*w4[2] + c[3]*w4[3];
      }
    }
    #pragma unroll
    for (int g = 0; g < 4; ++g) {
      float r = fmaxf(a2[g], 0.f);
      #pragma unroll
      for (int rr = 0; rr < 8; ++rr)
        out[(size_t)(rowbase + (4*hf+g)*8 + rr)*HIDN + col] = r;
    }
  }
}

extern "C" void kernel_launch(void* const* d_in, const int* in_sizes, int n_in,
                              void* d_out, int out_size, void* d_ws, size_t ws_size,
                              hipStream_t stream) {
    const float* hs    = (const float*)d_in[0];
    const float* eps   = (const float*)d_in[1];
    const float* WQ    = (const float*)d_in[2];
    const float* bQ    = (const float*)d_in[3];
    const float* WK    = (const float*)d_in[4];
    const float* bK    = (const float*)d_in[5];
    const float* Wmu   = (const float*)d_in[6];
    const float* bmu   = (const float*)d_in[7];
    const float* Wvar  = (const float*)d_in[8];
    const float* bvar  = (const float*)d_in[9];
    const float* vocab = (const float*)d_in[10];
    const float* Wsum  = (const float*)d_in[11];
    const float* bsum  = (const float*)d_in[12];
    const float* Whead = (const float*)d_in[13];
    const float* bhead = (const float*)d_in[14];
    float* o = (float*)d_out;
    float* wsf = (float*)d_ws;
    int Btot = in_sizes[0] / HIDN;
    hipLaunchKernelGGL(sort_vocab, dim3(32), dim3(256), 0, stream, vocab, Wmu, Wvar, wsf);
    hipLaunchKernelGGL(mac_fused, dim3(Btot / ROWSB), dim3(BLK), 0, stream,
                       hs, eps, WQ, bQ, WK, bK, Wmu, bmu, Wvar, bvar,
                       vocab, Wsum, bsum, Whead, bhead, wsf, o, Btot);
}

// Round 10
// 391.302 us; speedup vs baseline: 1.1835x; 1.0626x over previous
//
#include <hip/hip_runtime.h>

#define ROWSB 32     // rows per block; 4 waves x 8 rows (wave == agent group)
#define HIDN 256
#define TT 8
#define EPSI 1e-6f
#define HAS 260      // ha/vbuf row stride (floats)
#define SVS 260      // sorted-vocab row stride in ws (257 used + 3 INF pad)
#define TBSTR 40
#define NCELL 512
#define WS_LUT_F   (32*SVS)                 // ushort lut[32][512] == 8192 floats
#define WS_DINFO_F (32*SVS + 8192)          // float2 dinfo[32] (base, scale)
#define WS_WMV_F   (32*SVS + 8192 + 64)     // interleaved [j][d][(mu,var)] = 16384 floats

__device__ __forceinline__ void ld4(float* d, const float* p) {
  float4 v = *(const float4*)p;
  d[0] = v.x; d[1] = v.y; d[2] = v.z; d[3] = v.w;
}
__device__ __forceinline__ void ld2(float* d, const float* p) {
  float2 v = *(const float2*)p;
  d[0] = v.x; d[1] = v.y;
}
// Order own-wave LDS write->read without draining the global-load (vmcnt) queue.
__device__ __forceinline__ void lds_fence() {
  asm volatile("s_waitcnt lgkmcnt(0)" ::: "memory");
}
// 8 FMAs for one j: wv = (mu[d0],var[d0],mu[d1],var[d1]); h0/h1 = ha[row0/1][j]
__device__ __forceinline__ void fma8(float4 wv, float h0, float h1,
                                     float* mu0, float* lv0, float* mu1, float* lv1) {
  mu0[0] += h0*wv.x; lv0[0] += h0*wv.y; mu0[1] += h0*wv.z; lv0[1] += h0*wv.w;
  mu1[0] += h1*wv.x; lv1[0] += h1*wv.y; mu1[1] += h1*wv.z; lv1[1] += h1*wv.w;
}

// ---------- pre-pass: per-dim bitonic sort + 512-cell LUT + (mu,var) weight interleave ----------
__global__ __launch_bounds__(256)
void sort_vocab(const float* __restrict__ vocab,
                const float* __restrict__ Wmu, const float* __restrict__ Wvar,
                float* __restrict__ ws) {
  __shared__ float arr[512];
  const int d = blockIdx.x;
  const int t = threadIdx.x;
  ws[WS_WMV_F + ((size_t)t*32 + d)*2 + 0] = Wmu[(size_t)t*32 + d];
  ws[WS_WMV_F + ((size_t)t*32 + d)*2 + 1] = Wvar[(size_t)t*32 + d];
  arr[t] = (t < 257) ? vocab[t*32 + d] : 3.0e38f;
  arr[t+256] = (t == 0) ? vocab[256*32 + d] : 3.0e38f;
  __syncthreads();
  for (int k = 2; k <= 512; k <<= 1) {
    for (int j = k >> 1; j > 0; j >>= 1) {
      #pragma unroll
      for (int h = 0; h < 2; ++h) {
        int i = t + h*256;
        int ixj = i ^ j;
        if (ixj > i) {
          float a = arr[i], b = arr[ixj];
          bool up = ((i & k) == 0);
          if ((a > b) == up) { arr[i] = b; arr[ixj] = a; }
        }
      }
      __syncthreads();
    }
  }
  #pragma unroll
  for (int h = 0; h < 2; ++h) {
    int i = t + h*256;
    if (i < SVS) ws[d*SVS + i] = (i < 257) ? arr[i] : 3.0e38f;
  }
  float base = arr[0];
  float maxv = arr[256];
  float scale = (float)NCELL / fmaxf(maxv - base, 1e-30f);
  if (t == 0) {
    float2* dinfo = (float2*)(ws + WS_DINFO_F);
    dinfo[d] = make_float2(base, scale);
  }
  #pragma unroll
  for (int h = 0; h < 2; ++h) {
    int cell = t + h*256;
    float target = base + (float)cell * (maxv - base) * (1.0f/(float)NCELL);
    int lo = 0, hi = 257;
    while (lo < hi) { int mid = (lo+hi)>>1; if (arr[mid] < target) lo = mid+1; else hi = mid; }
    ((unsigned short*)(ws + WS_LUT_F))[d*NCELL + cell] = (unsigned short)lo;
  }
}

// ---------- main fused kernel: 8 rows/wave; V evicted to LDS; global sorted scan ----------
// Register law on this part (r6-r9): <=128 VGPR <-> 2 waves/SIMD; >128 -> 1 wave/SIMD.
// Persistent state must stay well under 128 so the GEMV pipeline buffers spill less.
// V (static after the initial GEMM, read back by the SAME lane) lives in vbuf LDS.
__global__ __launch_bounds__(256, 2)
void mac_fused(const float* __restrict__ hs, const float* __restrict__ eps,
               const float* __restrict__ WQ, const float* __restrict__ bQ,
               const float* __restrict__ WK, const float* __restrict__ bK,
               const float* __restrict__ Wmu, const float* __restrict__ bmu,
               const float* __restrict__ Wvar, const float* __restrict__ bvar,
               const float* __restrict__ vocab,
               const float* __restrict__ Wsum, const float* __restrict__ bsum,
               const float* __restrict__ Whead, const float* __restrict__ bhead,
               const float* __restrict__ ws, float* __restrict__ out, int Btot)
{
  // 71,936 B LDS -> 2 blocks/CU
  __shared__ __align__(16) float ha[ROWSB*HAS];       // wave-private rows; end: comm/o1 alias
  __shared__ __align__(16) float vbuf[ROWSB*HAS];     // V, wave-private, written once
  __shared__ __align__(16) float tokbuf[ROWSB*TBSTR]; // wave-private rows
  __shared__ float ivbuf[ROWSB], finbuf[ROWSB];       // wave-private rows

  const int t   = threadIdx.x;
  const int c4  = t & 63;
  const int w   = t >> 6;         // wave id; rows w*8..w*8+7 (one agent group)
  const int rp  = t >> 4;         // sampling row-pair: rows 2rp, 2rp+1 (in own octet)
  const int dp  = t & 15;         // sampling dim-pair: dims 2dp, 2dp+1
  const int d0u = (c4 << 2) & 31;
  const int tg  = c4 >> 3;        // token slot of this thread's cols
  const int rowbase = blockIdx.x * ROWSB;

  float Qr[8][4], Kr[8][4], MSGr[8][4];
  float eosv[4];
  unsigned fin = 0u;

  // ---------------- staging (all wave-private) ----------------
  {
    const float* hp = hs + (size_t)(rowbase + w*8)*HIDN + c4*4;
    #pragma unroll
    for (int rr = 0; rr < 8; ++rr)
      *(float4*)&ha[(w*8+rr)*HAS + c4*4] = *(const float4*)(hp + (size_t)rr*HIDN);
  }
  if (c4 < 8) finbuf[w*8 + c4] = 0.f;
  ld4(eosv, vocab + 256*32 + d0u);
  float dbr[2], dsr[2];
  {
    float t0[4];
    ld4(t0, ws + WS_DINFO_F + dp*4);   // dinfo[2dp], dinfo[2dp+1]
    dbr[0]=t0[0]; dsr[0]=t0[1]; dbr[1]=t0[2]; dsr[1]=t0[3];
  }
  float bm[2], bv[2];
  ld2(bm, bmu + dp*2); ld2(bv, bvar + dp*2);
  lds_fence();   // own-wave ha writes ordered before cross-lane reads

  // ------------- initial GEMM: Q = hs@WQ + bQ ; V = hs@WK + bK (V -> vbuf) -------------
  {
    float Vr[8][4];
    {
      float bq[4], bk[4];
      ld4(bq, bQ + c4*4); ld4(bk, bK + c4*4);
      #pragma unroll
      for (int rr = 0; rr < 8; ++rr) {
        #pragma unroll
        for (int k = 0; k < 4; ++k) { Qr[rr][k] = bq[k]; Vr[rr][k] = bk[k]; }
      }
    }
    #pragma unroll 2
    for (int jq = 0; jq < 64; ++jq) {
      float hsq[8][4];
      #pragma unroll
      for (int rr = 0; rr < 8; ++rr) ld4(hsq[rr], &ha[(w*8+rr)*HAS + jq*4]);
      #pragma unroll
      for (int m = 0; m < 4; ++m) {
        float wq[4], wk[4];
        ld4(wq, WQ + (size_t)(jq*4+m)*HIDN + c4*4);
        ld4(wk, WK + (size_t)(jq*4+m)*HIDN + c4*4);
        #pragma unroll
        for (int rr = 0; rr < 8; ++rr) {
          #pragma unroll
          for (int k = 0; k < 4; ++k) {
            Qr[rr][k] += hsq[rr][m]*wq[k];
            Vr[rr][k] += hsq[rr][m]*wk[k];
          }
        }
      }
    }
    // park V in LDS (same lane writes and later reads these addresses)
    #pragma unroll
    for (int rr = 0; rr < 8; ++rr)
      *(float4*)&vbuf[(w*8+rr)*HAS + c4*4] =
          make_float4(Vr[rr][0], Vr[rr][1], Vr[rr][2], Vr[rr][3]);
  }
  {
    float bk[4]; ld4(bk, bK + c4*4);
    #pragma unroll
    for (int rr = 0; rr < 8; ++rr) {
      #pragma unroll
      for (int k = 0; k < 4; ++k) {
        Qr[rr][k] *= (1.0f/256.0f);   // bake NF^2: logit = -(Qr*Kr)
        Kr[rr][k]   = bk[k];
        MSGr[rr][k] = 0.f;
      }
    }
  }
  lds_fence();

  // ---------------- token recurrence (wave-private; zero block barriers) ----------------
  for (int it = 0; it < TT; ++it) {
    if (it > 0) {
      const float* Wr = WK + (size_t)((it-1)*32)*HIDN + c4*4;
      #pragma unroll 2
      for (int cq = 0; cq < 8; ++cq) {
        float tq[8][4];
        #pragma unroll
        for (int rr = 0; rr < 8; ++rr) ld4(tq[rr], &tokbuf[(w*8+rr)*TBSTR + cq*4]);
        #pragma unroll
        for (int m = 0; m < 4; ++m) {
          float wv[4]; ld4(wv, Wr + (size_t)(cq*4+m)*HIDN);
          #pragma unroll
          for (int rr = 0; rr < 8; ++rr) {
            #pragma unroll
            for (int k = 0; k < 4; ++k) Kr[rr][k] += tq[rr][m]*wv[k];
          }
        }
      }
    }

    // eps prefetch for both sampling rows
    float ep0[2], ep1[2];
    ld2(ep0, eps + ((size_t)it*Btot + rowbase + 2*rp)*32 + dp*2);
    ld2(ep1, eps + ((size_t)it*Btot + rowbase + 2*rp+1)*32 + dp*2);

    // --- softmax(-(Q*K)) without max-sub (|logit|<~2e-3); store e*V; 1/s in ivbuf ---
    #pragma unroll
    for (int rr = 0; rr < 8; ++rr) {
      float e[4]; float s = 0.f;
      #pragma unroll
      for (int k = 0; k < 4; ++k) { e[k] = __expf(-(Qr[rr][k]*Kr[rr][k])); s += e[k]; }
      #pragma unroll
      for (int off = 32; off >= 1; off >>= 1) s += __shfl_xor(s, off);
      if (c4 == rr) ivbuf[w*8+rr] = 1.0f / s;
      float vv[4];
      ld4(vv, &vbuf[(w*8+rr)*HAS + c4*4]);   // own-lane V readback
      *(float4*)&ha[(w*8+rr)*HAS + c4*4] =
          make_float4(e[0]*vv[0], e[1]*vv[1], e[2]*vv[2], e[3]*vv[3]);
    }
    lds_fence();

    // --- GEMV (2 rows x 2 dims/thread, reg-double-buffered weight stream) ---
    float mu0[2]={0,0}, lv0[2]={0,0}, mu1[2]={0,0}, lv1[2]={0,0};
    {
      const float* wmv  = ws + WS_WMV_F + dp*4;   // + j*64 per weight row j
      const float* har0 = &ha[(2*rp)*HAS];
      const float* har1 = &ha[(2*rp+1)*HAS];
      float4 wb0[8], wb1[8];
      #pragma unroll
      for (int u = 0; u < 8; ++u) wb0[u] = *(const float4*)(wmv + (size_t)u*64);
      #pragma unroll 1
      for (int bb = 0; bb < 16; ++bb) {
        {   // batch b = 2bb (weights in wb0); prefetch b+1 into wb1
          const int b = 2*bb;
          float4 h0a = *(const float4*)(har0 + b*8);
          float4 h1a = *(const float4*)(har1 + b*8);
          float4 h0b = *(const float4*)(har0 + b*8 + 4);
          float4 h1b = *(const float4*)(har1 + b*8 + 4);
          const float* wp = wmv + (size_t)(b+1)*512;
          #pragma unroll
          for (int u = 0; u < 8; ++u) wb1[u] = *(const float4*)(wp + (size_t)u*64);
          fma8(wb0[0], h0a.x, h1a.x, mu0, lv0, mu1, lv1);
          fma8(wb0[1], h0a.y, h1a.y, mu0, lv0, mu1, lv1);
          fma8(wb0[2], h0a.z, h1a.z, mu0, lv0, mu1, lv1);
          fma8(wb0[3], h0a.w, h1a.w, mu0, lv0, mu1, lv1);
          fma8(wb0[4], h0b.x, h1b.x, mu0, lv0, mu1, lv1);
          fma8(wb0[5], h0b.y, h1b.y, mu0, lv0, mu1, lv1);
          fma8(wb0[6], h0b.z, h1b.z, mu0, lv0, mu1, lv1);
          fma8(wb0[7], h0b.w, h1b.w, mu0, lv0, mu1, lv1);
        }
        {   // batch b = 2bb+1 (weights in wb1); prefetch b+1 into wb0
          const int b = 2*bb+1;
          float4 h0a = *(const float4*)(har0 + b*8);
          float4 h1a = *(const float4*)(har1 + b*8);
          float4 h0b = *(const float4*)(har0 + b*8 + 4);
          float4 h1b = *(const float4*)(har1 + b*8 + 4);
          if (bb < 15) {
            const float* wp = wmv + (size_t)(b+1)*512;
            #pragma unroll
            for (int u = 0; u < 8; ++u) wb0[u] = *(const float4*)(wp + (size_t)u*64);
          }
          fma8(wb1[0], h0a.x, h1a.x, mu0, lv0, mu1, lv1);
          fma8(wb1[1], h0a.y, h1a.y, mu0, lv0, mu1, lv1);
          fma8(wb1[2], h0a.z, h1a.z, mu0, lv0, mu1, lv1);
          fma8(wb1[3], h0a.w, h1a.w, mu0, lv0, mu1, lv1);
          fma8(wb1[4], h0b.x, h1b.x, mu0, lv0, mu1, lv1);
          fma8(wb1[5], h0b.y, h1b.y, mu0, lv0, mu1, lv1);
          fma8(wb1[6], h0b.z, h1b.z, mu0, lv0, mu1, lv1);
          fma8(wb1[7], h0b.w, h1b.w, mu0, lv0, mu1, lv1);
        }
      }
    }
    // --- sample + quantize via sorted scan (global, L2-hot, NCELL=512) ---
    {
      float ivr0 = ivbuf[2*rp],  ivr1 = ivbuf[2*rp+1];
      float msk0 = 1.0f - finbuf[2*rp], msk1 = 1.0f - finbuf[2*rp+1];
      const unsigned short* lutg = (const unsigned short*)(ws + WS_LUT_F);
      float md0[2], md1[2];
      #pragma unroll
      for (int d = 0; d < 2; ++d) {
        const int dim = 2*dp + d;
        const float* sp = ws + dim*SVS;
        {
          float mu = mu0[d]*ivr0 + bm[d];
          float lv = lv0[d]*ivr0 + bv[d];
          float x  = ep0[d]*__expf(0.5f*lv) + mu;
          int c = (int)((x - dbr[d]) * dsr[d]);
          c = min(max(c, 0), NCELL-1);
          int idx = (int)lutg[dim*NCELL + c];
          float v = sp[idx];
          while (v < x) { ++idx; v = sp[idx]; }   // pads +INF -> terminates
          float dn = v - x;
          float dpv = (idx > 0) ? (x - sp[idx-1]) : 3.0e38f;
          md0[d] = fminf(dn, dpv);
        }
        {
          float mu = mu1[d]*ivr1 + bm[d];
          float lv = lv1[d]*ivr1 + bv[d];
          float x  = ep1[d]*__expf(0.5f*lv) + mu;
          int c = (int)((x - dbr[d]) * dsr[d]);
          c = min(max(c, 0), NCELL-1);
          int idx = (int)lutg[dim*NCELL + c];
          float v = sp[idx];
          while (v < x) { ++idx; v = sp[idx]; }
          float dn = v - x;
          float dpv = (idx > 0) ? (x - sp[idx-1]) : 3.0e38f;
          md1[d] = fminf(dn, dpv);
        }
      }
      *(float2*)&tokbuf[(2*rp)*TBSTR + dp*2]   = make_float2(md0[0]*md0[0]*msk0, md0[1]*md0[1]*msk0);
      *(float2*)&tokbuf[(2*rp+1)*TBSTR + dp*2] = make_float2(md1[0]*md1[0]*msk1, md1[1]*md1[1]*msk1);
    }
    lds_fence();

    // --- hit detection + message update ---
    {
      float tokr[8][4];
      #pragma unroll
      for (int rr = 0; rr < 8; ++rr) ld4(tokr[rr], &tokbuf[(w*8+rr)*TBSTR + d0u]);
      unsigned newfin = fin;
      #pragma unroll
      for (int rr = 0; rr < 8; ++rr) {
        float pd = 0.f, ed = 0.f;
        #pragma unroll
        for (int k = 0; k < 4; ++k) { float dm = tokr[rr][k]-MSGr[rr][k]; pd += dm*dm; }
        if (tg == 0) {
          #pragma unroll
          for (int k = 0; k < 4; ++k) { float de = tokr[rr][k]-eosv[k]; ed += de*de; }
        }
        pd += __shfl_xor(pd, 1); ed += __shfl_xor(ed, 1);
        pd += __shfl_xor(pd, 2); ed += __shfl_xor(ed, 2);
        pd += __shfl_xor(pd, 4); ed += __shfl_xor(ed, 4);
        bool lane_hit = (tg < it && pd < EPSI) || (tg == 0 && ed < EPSI);
        bool hit = (__ballot(lane_hit) != 0ull);
        if (hit) {
          if ((tg == it) && !((fin >> rr) & 1u)) {
            #pragma unroll
            for (int k = 0; k < 4; ++k) tokr[rr][k] = eosv[k];
          }
          newfin |= (1u << rr);
        }
        if (tg == it) {
          #pragma unroll
          for (int k = 0; k < 4; ++k) MSGr[rr][k] = tokr[rr][k];
        }
      }
      if (tg == it) {
        #pragma unroll
        for (int rr = 0; rr < 8; ++rr)
          *(float4*)&tokbuf[(w*8+rr)*TBSTR + d0u] =
              make_float4(MSGr[rr][0], MSGr[rr][1], MSGr[rr][2], MSGr[rr][3]);
      }
      if (c4 < 8) finbuf[w*8+c4] = ((newfin >> c4) & 1u) ? 1.f : 0.f;
      fin = newfin;
    }
    lds_fence();
  }

  // ---------------- final: comm sum + two block-coop GEMVs + relu ----------------
  __syncthreads();                 // all waves done with ha before aliasing
  float* commb = ha;               // [4][HAS] rows 0..3
  float* o1    = ha + 4*HAS;       // [4][HAS] rows 4..7
  {
    float cs[4] = {0,0,0,0};
    #pragma unroll
    for (int rr = 0; rr < 8; ++rr) {
      #pragma unroll
      for (int k = 0; k < 4; ++k) cs[k] += MSGr[rr][k];
    }
    const float i7 = 1.0f/7.0f;
    *(float4*)&commb[w*HAS + c4*4] = make_float4(cs[0]*i7, cs[1]*i7, cs[2]*i7, cs[3]*i7);
  }
  __syncthreads();
  {
    float bs = bsum[t];
    float a1[4] = {bs, bs, bs, bs};
    #pragma unroll 2
    for (int jq = 0; jq < 64; ++jq) {
      float w4[4];
      #pragma unroll
      for (int m = 0; m < 4; ++m) w4[m] = Wsum[(size_t)(jq*4+m)*HIDN + t];
      #pragma unroll
      for (int g = 0; g < 4; ++g) {
        float c[4]; ld4(c, &commb[g*HAS + jq*4]);   // uniform broadcast
        a1[g] += c[0]*w4[0] + c[1]*w4[1] + c[2]*w4[2] + c[3]*w4[3];
      }
    }
    #pragma unroll
    for (int g = 0; g < 4; ++g) o1[g*HAS + t] = a1[g];
  }
  __syncthreads();
  {
    float bh = bhead[t];
    float a2[4] = {bh, bh, bh, bh};
    #pragma unroll 2
    for (int jq = 0; jq < 64; ++jq) {
      float w4[4];
      #pragma unroll
      for (int m = 0; m < 4; ++m) w4[m] = Whead[(size_t)(jq*4+m)*HIDN + t];
      #pragma unroll
      for (int g = 0; g < 4; ++g) {
        float c[4]; ld4(c, &o1[g*HAS + jq*4]);
        a2[g] += c[0]*w4[0] + c[1]*w4[1] + c[2]*w4[2] + c[3]*w4[3];
      }
    }
    #pragma unroll
    for (int g = 0; g < 4; ++g) {
      float r = fmaxf(a2[g], 0.f);
      #pragma unroll
      for (int rr = 0; rr < 8; ++rr)
        out[(size_t)(rowbase + g*8 + rr)*HIDN + t] = r;
    }
  }
}

extern "C" void kernel_launch(void* const* d_in, const int* in_sizes, int n_in,
                              void* d_out, int out_size, void* d_ws, size_t ws_size,
                              hipStream_t stream) {
    const float* hs    = (const float*)d_in[0];
    const float* eps   = (const float*)d_in[1];
    const float* WQ    = (const float*)d_in[2];
    const float* bQ    = (const float*)d_in[3];
    const float* WK    = (const float*)d_in[4];
    const float* bK    = (const float*)d_in[5];
    const float* Wmu   = (const float*)d_in[6];
    const float* bmu   = (const float*)d_in[7];
    const float* Wvar  = (const float*)d_in[8];
    const float* bvar  = (const float*)d_in[9];
    const float* vocab = (const float*)d_in[10];
    const float* Wsum  = (const float*)d_in[11];
    const float* bsum  = (const float*)d_in[12];
    const float* Whead = (const float*)d_in[13];
    const float* bhead = (const float*)d_in[14];
    float* o = (float*)d_out;
    float* wsf = (float*)d_ws;
    int Btot = in_sizes[0] / HIDN;
    hipLaunchKernelGGL(sort_vocab, dim3(32), dim3(256), 0, stream, vocab, Wmu, Wvar, wsf);
    hipLaunchKernelGGL(mac_fused, dim3(Btot / ROWSB), dim3(256), 0, stream,
                       hs, eps, WQ, bQ, WK, bK, Wmu, bmu, Wvar, bvar,
                       vocab, Wsum, bsum, Whead, bhead, wsf, o, Btot);
}